// Round 10
// baseline (163.601 us; speedup 1.0000x reference)
//
#include <hip/hip_runtime.h>
#include <stdint.h>

// Problem constants (static per reference)
#define NG    256    // graphs
#define NPG   128    // nodes per graph
#define PP    8      // perturbations
#define IND   64     // input dim
#define HID   128    // hidden
#define OUTD  10     // classes

typedef short bf16x8 __attribute__((ext_vector_type(8)));
typedef float f32x4  __attribute__((ext_vector_type(4)));

// RNE f32->bf16 (bit trick) — the verified-correct conversion on this path.
static __device__ __forceinline__ unsigned short f2bf(float f) {
    unsigned int u = __float_as_uint(f);
    u += 0x7FFFu + ((u >> 16) & 1u);
    return (unsigned short)(u >> 16);
}

static __device__ __forceinline__ f32x4 mfma16(bf16x8 a, bf16x8 b, f32x4 c) {
    return __builtin_amdgcn_mfma_f32_16x16x32_bf16(a, b, c, 0, 0, 0);
}

// ws layout:
//   shorts [0)      W1t  128x64   (Wt[out][in])
//   shorts [8192)   W2t  128x128
//   shorts [24576)  Wg1t 128x128
//   shorts [40960)  Wg2t 128x128
//   shorts [57344)  Wb1t 128x128
//   shorts [73728)  Wb2t 128x128
//   bytes  [180224) partial 512x128 fp32 (half-graph pools)
#define PART_BYTE 180224

#define LSTR 136   // bf16 LDS row stride for 128-col tiles (272 B): 68 words
                   // == 4 mod 32 -> only 2-way bank aliasing (free)
#define XBS  72    // x-slab stride (64 cols + pad): 36 words == 4 mod 32, same

// ---------------------------------------------------------------------------
// Kernel 0: convert + transpose weights (coalesced writes; src stays in L2)
// ---------------------------------------------------------------------------
__global__ void prep_weights(const float* __restrict__ Wl1, const float* __restrict__ Wl2,
                             const float* __restrict__ Wg1, const float* __restrict__ Wg2,
                             const float* __restrict__ Wb1, const float* __restrict__ Wb2,
                             unsigned short* __restrict__ ws) {
    int e = blockIdx.x * blockDim.x + threadIdx.x;
    if (e < 8192) {
        int n = e >> 6, k = e & 63;
        ws[e] = f2bf(Wl1[k * HID + n]);
        return;
    }
    int e2 = e - 8192;
    int m = e2 >> 14;
    int idx = e2 & 16383;
    int n = idx >> 7, k = idx & 127;
    const float* src;
    if      (m == 0) src = Wl2;
    else if (m == 1) src = Wg1;
    else if (m == 2) src = Wg2;
    else if (m == 3) src = Wb1;
    else             src = Wb2;
    ws[8192 + m * 16384 + idx] = f2bf(src[k * HID + n]);
}

// ---------------------------------------------------------------------------
// Kernel 1: HALF-GRAPH fused. 512 blocks x 256 threads (4 waves), 53.8 KB LDS
// -> 2+ independent blocks/CU whose barrier phases interleave (the axis
// r6-r9 never varied: those were all 1 barrier-locked block/CU and sat at an
// invariant 42 us with nothing saturated = serial phase chain).
// Phase A: 4 node-tiles, per-tile body = round-5's proven local_mlp (x staged
// bf16 once, two 4-perturbation halves through a 64-row h1). Agg slices kept
// in regs (static unroll), then materialized to LDS.
// Phase B: round-2's proven global_layers half-graph body (64 rows, 4 layers,
// ping-pong aggL <-> bufB aliasing the dead x buffer), partial pool to ws.
// Decoder runs as the tiny proven kernel 2.
// ---------------------------------------------------------------------------
__global__ __launch_bounds__(256, 3) void half_fused(
    const float* __restrict__ x,
    const unsigned short* __restrict__ wt,
    const float* __restrict__ bl1, const float* __restrict__ bl2,
    const float* __restrict__ bg1, const float* __restrict__ bg2,
    const float* __restrict__ bb1, const float* __restrict__ bb2,
    float* __restrict__ partial)
{
    // LDS map (bytes):
    //   [0)      xb   128*XBS shorts (18432)  (phase B: bufB aliases, 17408)
    //   [18432)  h1    64*LSTR shorts (17408)
    //   [35840)  aggL  64*LSTR shorts (17408)
    //   [53248)  pool 128 f32 (512)
    __shared__ __align__(16) unsigned char smem[53760];
    unsigned short* xb   = (unsigned short*)(smem);
    unsigned short* h1   = (unsigned short*)(smem + 18432);
    unsigned short* aggL = (unsigned short*)(smem + 35840);
    unsigned short* bufB = (unsigned short*)(smem);           // phase-B ping
    float* pool = (float*)(smem + 53248);

    const int g    = blockIdx.x >> 1;
    const int hh   = blockIdx.x & 1;    // which half: nodes [64*hh, 64*hh+64)
    const int tid  = threadIdx.x;
    const int wave = tid >> 6;          // 0..3
    const int lane = tid & 63;
    const int q    = lane >> 4;
    const int r    = lane & 15;
    const int ot0  = wave * 2;          // wave owns out cols [32*wave, +32)

    const float* xg = x + (size_t)g * (NPG * PP) * IND;

    // ---- weight fragments + biases (round-5 exact) ----
    bf16x8 w1f[2][2];
#pragma unroll
    for (int t = 0; t < 2; ++t)
#pragma unroll
        for (int ks = 0; ks < 2; ++ks)
            w1f[t][ks] = *(const bf16x8*)(wt + ((ot0 + t) * 16 + r) * 64 + ks * 32 + q * 8);

    const unsigned short* w2t = wt + 8192;
    bf16x8 w2f[2][4];
#pragma unroll
    for (int t = 0; t < 2; ++t)
#pragma unroll
        for (int ks = 0; ks < 4; ++ks)
            w2f[t][ks] = *(const bf16x8*)(w2t + ((ot0 + t) * 16 + r) * 128 + ks * 32 + q * 8);

    float4 b1s[2], b2s[2];
#pragma unroll
    for (int t = 0; t < 2; ++t) {
        int ob = (ot0 + t) * 16 + q * 4;
        b1s[t] = *(const float4*)(bl1 + ob);
        b2s[t] = *(const float4*)(bl2 + ob);
    }

    ushort4 aggv0[4], aggv1[4];   // per-tile agg slices (static-indexed)

    // ======================= phase A: 4 node-tiles =========================
#pragma unroll
    for (int t4 = 0; t4 < 4; ++t4) {
        // ---- stage this tile's x slab (128 rows x 64 f32) as bf16 ----
        // LDS row s = p*16+rr <-> global row p*128 + hh*64 + t4*16 + rr
#pragma unroll
        for (int it = 0; it < 8; ++it) {
            int e = it * 1024 + tid * 4;
            int s = e >> 6, col = e & 63;
            int p = s >> 4, rr = s & 15;
            float4 v = *(const float4*)(xg + (size_t)(p * 128 + hh * 64 + t4 * 16 + rr) * IND + col);
            ushort4 w4;
            w4.x = f2bf(v.x);
            w4.y = f2bf(v.y);
            w4.z = f2bf(v.z);
            w4.w = f2bf(v.w);
            *(ushort4*)(&xb[s * XBS + col]) = w4;
        }
        __syncthreads();   // xb staged (also: h1 readers of prev tile done)

        f32x4 agg0 = (f32x4){0.f, 0.f, 0.f, 0.f};
        f32x4 agg1 = (f32x4){0.f, 0.f, 0.f, 0.f};

        // ---- two halves of 4 perturbations (round-5 exact) ----
#pragma unroll
        for (int ph = 0; ph < 2; ++ph) {
#pragma unroll
            for (int p4 = 0; p4 < 4; ++p4) {
                const int p = ph * 4 + p4;
                f32x4 a0 = (f32x4){0.f, 0.f, 0.f, 0.f};
                f32x4 a1 = (f32x4){0.f, 0.f, 0.f, 0.f};
#pragma unroll
                for (int ks = 0; ks < 2; ++ks) {
                    bf16x8 xf = *(const bf16x8*)(&xb[(p * 16 + r) * XBS + ks * 32 + q * 8]);
                    a0 = mfma16(w1f[0][ks], xf, a0);
                    a1 = mfma16(w1f[1][ks], xf, a1);
                }
                ushort4 v0, v1;
                v0.x = f2bf(fmaxf(a0[0] + b1s[0].x, 0.f));
                v0.y = f2bf(fmaxf(a0[1] + b1s[0].y, 0.f));
                v0.z = f2bf(fmaxf(a0[2] + b1s[0].z, 0.f));
                v0.w = f2bf(fmaxf(a0[3] + b1s[0].w, 0.f));
                v1.x = f2bf(fmaxf(a1[0] + b1s[1].x, 0.f));
                v1.y = f2bf(fmaxf(a1[1] + b1s[1].y, 0.f));
                v1.z = f2bf(fmaxf(a1[2] + b1s[1].z, 0.f));
                v1.w = f2bf(fmaxf(a1[3] + b1s[1].w, 0.f));
                *(ushort4*)(&h1[(p4 * 16 + r) * LSTR + (ot0 + 0) * 16 + q * 4]) = v0;
                *(ushort4*)(&h1[(p4 * 16 + r) * LSTR + (ot0 + 1) * 16 + q * 4]) = v1;
            }
            __syncthreads();   // h1 (64 rows) complete

#pragma unroll
            for (int p4 = 0; p4 < 4; ++p4) {
                f32x4 c0 = (f32x4){0.f, 0.f, 0.f, 0.f};
                f32x4 c1 = (f32x4){0.f, 0.f, 0.f, 0.f};
#pragma unroll
                for (int ks = 0; ks < 4; ++ks) {
                    bf16x8 hf = *(const bf16x8*)(&h1[(p4 * 16 + r) * LSTR + ks * 32 + q * 8]);
                    c0 = mfma16(w2f[0][ks], hf, c0);
                    c1 = mfma16(w2f[1][ks], hf, c1);
                }
                agg0[0] += fmaxf(c0[0] + b2s[0].x, 0.f);
                agg0[1] += fmaxf(c0[1] + b2s[0].y, 0.f);
                agg0[2] += fmaxf(c0[2] + b2s[0].z, 0.f);
                agg0[3] += fmaxf(c0[3] + b2s[0].w, 0.f);
                agg1[0] += fmaxf(c1[0] + b2s[1].x, 0.f);
                agg1[1] += fmaxf(c1[1] + b2s[1].y, 0.f);
                agg1[2] += fmaxf(c1[2] + b2s[1].z, 0.f);
                agg1[3] += fmaxf(c1[3] + b2s[1].w, 0.f);
            }
            __syncthreads();   // all waves done reading h1
        }

        aggv0[t4].x = f2bf(agg0[0]);
        aggv0[t4].y = f2bf(agg0[1]);
        aggv0[t4].z = f2bf(agg0[2]);
        aggv0[t4].w = f2bf(agg0[3]);
        aggv1[t4].x = f2bf(agg1[0]);
        aggv1[t4].y = f2bf(agg1[1]);
        aggv1[t4].z = f2bf(agg1[2]);
        aggv1[t4].w = f2bf(agg1[3]);
    }

    // materialize agg (64 rows of this half) into aggL; lane-exclusive 8B
#pragma unroll
    for (int t4 = 0; t4 < 4; ++t4) {
        *(ushort4*)(&aggL[(t4 * 16 + r) * LSTR + (ot0 + 0) * 16 + q * 4]) = aggv0[t4];
        *(ushort4*)(&aggL[(t4 * 16 + r) * LSTR + (ot0 + 1) * 16 + q * 4]) = aggv1[t4];
    }
    __syncthreads();

    // ======== phase B: 4x (Linear+ReLU) on 64 rows + pool (round-2) ========
    int cur = 0;
#pragma unroll
    for (int l = 0; l < 4; ++l) {
        const unsigned short* wl = wt + 24576 + l * 16384;
        const float* bl = (l == 0) ? bg1 : (l == 1) ? bg2 : (l == 2) ? bb1 : bb2;

        bf16x8 wf[2][4];
#pragma unroll
        for (int t = 0; t < 2; ++t)
#pragma unroll
            for (int ks = 0; ks < 4; ++ks)
                wf[t][ks] = *(const bf16x8*)(wl + ((ot0 + t) * 16 + r) * 128 + ks * 32 + q * 8);

        unsigned short* Xb = cur ? bufB : aggL;
        unsigned short* Yb = cur ? aggL : bufB;

        f32x4 acc[2][4];
#pragma unroll
        for (int t = 0; t < 2; ++t)
#pragma unroll
            for (int j = 0; j < 4; ++j)
                acc[t][j] = (f32x4){0.f, 0.f, 0.f, 0.f};

#pragma unroll
        for (int ks = 0; ks < 4; ++ks) {
#pragma unroll
            for (int j = 0; j < 4; ++j) {
                int row = j * 16 + r;
                bf16x8 xf = *(const bf16x8*)(&Xb[row * LSTR + ks * 32 + q * 8]);
                acc[0][j] = mfma16(wf[0][ks], xf, acc[0][j]);
                acc[1][j] = mfma16(wf[1][ks], xf, acc[1][j]);
            }
        }

        if (l < 3) {
#pragma unroll
            for (int t = 0; t < 2; ++t) {
                int ob = (ot0 + t) * 16 + q * 4;
                float4 bs = *(const float4*)(bl + ob);
#pragma unroll
                for (int j = 0; j < 4; ++j) {
                    int row = j * 16 + r;
                    ushort4 v;
                    v.x = f2bf(fmaxf(acc[t][j][0] + bs.x, 0.f));
                    v.y = f2bf(fmaxf(acc[t][j][1] + bs.y, 0.f));
                    v.z = f2bf(fmaxf(acc[t][j][2] + bs.z, 0.f));
                    v.w = f2bf(fmaxf(acc[t][j][3] + bs.w, 0.f));
                    *(ushort4*)(&Yb[row * LSTR + ob]) = v;
                }
            }
            __syncthreads();
            cur ^= 1;
        } else {
            float s[2][4];
#pragma unroll
            for (int t = 0; t < 2; ++t) {
                int ob = (ot0 + t) * 16 + q * 4;
                float4 bs = *(const float4*)(bl + ob);
                s[t][0] = s[t][1] = s[t][2] = s[t][3] = 0.f;
#pragma unroll
                for (int j = 0; j < 4; ++j) {
                    s[t][0] += fmaxf(acc[t][j][0] + bs.x, 0.f);
                    s[t][1] += fmaxf(acc[t][j][1] + bs.y, 0.f);
                    s[t][2] += fmaxf(acc[t][j][2] + bs.z, 0.f);
                    s[t][3] += fmaxf(acc[t][j][3] + bs.w, 0.f);
                }
            }
#pragma unroll
            for (int m = 1; m < 16; m <<= 1) {
#pragma unroll
                for (int t = 0; t < 2; ++t)
#pragma unroll
                    for (int i = 0; i < 4; ++i)
                        s[t][i] += __shfl_xor(s[t][i], m, 64);
            }
            if (r == 0) {
#pragma unroll
                for (int t = 0; t < 2; ++t)
#pragma unroll
                    for (int i = 0; i < 4; ++i)
                        pool[(ot0 + t) * 16 + q * 4 + i] = s[t][i];  // exclusive cols/wave
            }
        }
    }
    __syncthreads();
    if (tid < HID) partial[(size_t)blockIdx.x * HID + tid] = pool[tid];
}

// ---------------------------------------------------------------------------
// Kernel 2: decoder + log_softmax (round-2 proven). 256 blocks x 64 threads.
// ---------------------------------------------------------------------------
__global__ void decoder_k(const float* __restrict__ partial,
                          const float* __restrict__ Wd1, const float* __restrict__ bd1,
                          const float* __restrict__ Wd2, const float* __restrict__ bd2,
                          float* __restrict__ out)
{
    __shared__ float pooled[HID];
    __shared__ float z[64];
    __shared__ float zz[OUTD];

    const int g = blockIdx.x;
    const int t = threadIdx.x;

    const float* p0 = partial + (size_t)(2 * g) * HID;
    const float* p1 = p0 + HID;
    pooled[t]      = p0[t]      + p1[t];
    pooled[t + 64] = p0[t + 64] + p1[t + 64];
    __syncthreads();

    float a0 = bd1[t], a1 = 0.f, a2 = 0.f, a3 = 0.f;
#pragma unroll
    for (int k = 0; k < 128; k += 4) {
        a0 += pooled[k]     * Wd1[(k)     * 64 + t];
        a1 += pooled[k + 1] * Wd1[(k + 1) * 64 + t];
        a2 += pooled[k + 2] * Wd1[(k + 2) * 64 + t];
        a3 += pooled[k + 3] * Wd1[(k + 3) * 64 + t];
    }
    z[t] = fmaxf((a0 + a1) + (a2 + a3), 0.f);
    __syncthreads();

    if (t < OUTD) {
        float b0 = bd2[t], b1 = 0.f;
#pragma unroll
        for (int k = 0; k < 64; k += 2) {
            b0 += z[k]     * Wd2[(k)     * OUTD + t];
            b1 += z[k + 1] * Wd2[(k + 1) * OUTD + t];
        }
        zz[t] = b0 + b1;
    }
    __syncthreads();
    if (t == 0) {
        float m = -1e30f;
#pragma unroll
        for (int j = 0; j < OUTD; ++j) m = fmaxf(m, zz[j]);
        float ssum = 0.f;
#pragma unroll
        for (int j = 0; j < OUTD; ++j) ssum += expf(zz[j] - m);
        float ls = logf(ssum);
#pragma unroll
        for (int j = 0; j < OUTD; ++j) out[g * OUTD + j] = zz[j] - m - ls;
    }
}

extern "C" void kernel_launch(void* const* d_in, const int* in_sizes, int n_in,
                              void* d_out, int out_size, void* d_ws, size_t ws_size,
                              hipStream_t stream) {
    const float* x   = (const float*)d_in[0];
    // d_in[1] = ptr (unused; structure is static)
    const float* Wl1 = (const float*)d_in[2];
    const float* bl1 = (const float*)d_in[3];
    const float* Wl2 = (const float*)d_in[4];
    const float* bl2 = (const float*)d_in[5];
    const float* Wg1 = (const float*)d_in[6];
    const float* bg1 = (const float*)d_in[7];
    const float* Wg2 = (const float*)d_in[8];
    const float* bg2 = (const float*)d_in[9];
    const float* Wb1 = (const float*)d_in[10];
    const float* bb1 = (const float*)d_in[11];
    const float* Wb2 = (const float*)d_in[12];
    const float* bb2 = (const float*)d_in[13];
    const float* Wd1 = (const float*)d_in[14];
    const float* bd1 = (const float*)d_in[15];
    const float* Wd2 = (const float*)d_in[16];
    const float* bd2 = (const float*)d_in[17];

    unsigned short* ws = (unsigned short*)d_ws;
    float* partial     = (float*)((char*)d_ws + PART_BYTE);

    prep_weights<<<352, 256, 0, stream>>>(Wl1, Wl2, Wg1, Wg2, Wb1, Wb2, ws);
    half_fused<<<NG * 2, 256, 0, stream>>>(x, ws, bl1, bl2, bg1, bg2, bb1, bb2, partial);
    decoder_k<<<NG, 64, 0, stream>>>(partial, Wd1, bd1, Wd2, bd2, (float*)d_out);
}

// Round 11
// 143.582 us; speedup vs baseline: 1.1394x; 1.1394x over previous
//
#include <hip/hip_runtime.h>
#include <stdint.h>

// Problem constants (static per reference)
#define NG    256    // graphs
#define NPG   128    // nodes per graph
#define PP    8      // perturbations
#define IND   64     // input dim
#define HID   128    // hidden
#define OUTD  10     // classes

typedef short bf16x8 __attribute__((ext_vector_type(8)));
typedef float f32x4  __attribute__((ext_vector_type(4)));

// RNE f32->bf16 (bit trick) — the verified-correct conversion on this path.
static __device__ __forceinline__ unsigned short f2bf(float f) {
    unsigned int u = __float_as_uint(f);
    u += 0x7FFFu + ((u >> 16) & 1u);
    return (unsigned short)(u >> 16);
}

static __device__ __forceinline__ f32x4 mfma16(bf16x8 a, bf16x8 b, f32x4 c) {
    return __builtin_amdgcn_mfma_f32_16x16x32_bf16(a, b, c, 0, 0, 0);
}

// Build one bf16x8 A-fragment directly from the f32 weight matrix W[k][out]
// (k-major, HID out-cols): elements k0..k0+7 of column outc. Identical f2bf
// on identical f32 values as the old prep_weights kernel -> bit-identical
// fragments, no prep launch, no workspace.
static __device__ __forceinline__ bf16x8 fragW(const float* __restrict__ W,
                                               int outc, int k0) {
    bf16x8 f;
#pragma unroll
    for (int j = 0; j < 8; ++j)
        f[j] = (short)f2bf(W[(size_t)(k0 + j) * HID + outc]);
    return f;
}

#define LSTR 136   // bf16 LDS row stride for 128-col tiles (272 B): 68 words
                   // == 4 mod 32 -> only 2-way bank aliasing (free)
#define XBS  72    // x-slab stride (64 cols + pad): 36 words == 4 mod 32, same

// ---------------------------------------------------------------------------
// Fused kernel: ONE BLOCK PER GRAPH (256 blocks x 512 threads = 8 waves).
// This is the round-6 kernel (best measured: 143.2 us total) with ONE change:
// weight fragments are converted in-kernel from the f32 weights (fragW above),
// eliminating the prep_weights kernel and its launch boundary. Everything
// else — LDS map, staging, barriers, arithmetic, f2bf sites — is verbatim
// round-6 (r7/r8/r9/r10 restructures all measured equal or worse).
// ---------------------------------------------------------------------------
__global__ __launch_bounds__(512) void graph_fused(
    const float* __restrict__ x,
    const float* __restrict__ Wl1, const float* __restrict__ bl1,
    const float* __restrict__ Wl2, const float* __restrict__ bl2,
    const float* __restrict__ Wg1, const float* __restrict__ bg1,
    const float* __restrict__ Wg2, const float* __restrict__ bg2,
    const float* __restrict__ Wb1, const float* __restrict__ bb1,
    const float* __restrict__ Wb2, const float* __restrict__ bb2,
    const float* __restrict__ Wd1, const float* __restrict__ bd1,
    const float* __restrict__ Wd2, const float* __restrict__ bd2,
    float* __restrict__ out)
{
    // LDS map (bytes):
    //   [0)      xb0 128*XBS shorts (18432) \  phase A x dbuf; aliased by
    //   [18432)  xb1 128*XBS shorts (18432) /  bufB (34816 B) in phase B
    //   [36864)  h1   128*LSTR shorts (34816)
    //   [71680)  aggL 128*LSTR shorts (34816)
    //   [106496) pool 128 f32 (512)
    //   [107008) z    64 f32  (256)
    //   [107264) zz   16 f32  (64)
    __shared__ __align__(16) unsigned char smem[107328];
    unsigned short* xb0  = (unsigned short*)(smem);
    unsigned short* xb1  = (unsigned short*)(smem + 18432);
    unsigned short* h1   = (unsigned short*)(smem + 36864);
    unsigned short* aggL = (unsigned short*)(smem + 71680);
    unsigned short* bufB = (unsigned short*)(smem);            // phase-B ping
    float* pool = (float*)(smem + 106496);
    float* z    = (float*)(smem + 107008);
    float* zz   = (float*)(smem + 107264);

    const int g    = blockIdx.x;
    const int tid  = threadIdx.x;
    const int wave = tid >> 6;     // 0..7
    const int lane = tid & 63;
    const int q    = lane >> 4;
    const int r    = lane & 15;
    const int ot   = wave;         // each wave owns output cols [16*ot, 16*ot+16)

    const float* xg = x + (size_t)g * (NPG * PP) * IND;

    // ---- per-thread staging geometry: 8192 elems/tile, 16 per thread ----
    int sIt[4], cIt[4], gRow[4];
#pragma unroll
    for (int it = 0; it < 4; ++it) {
        int e = it * 2048 + tid * 4;       // element index in the tile slab
        int s = e >> 6;                    // LDS row (p*16 + rr)
        sIt[it]  = s;
        cIt[it]  = e & 63;
        gRow[it] = (s >> 4) * 128 + (s & 15);   // global row sans nt*16
    }
    float4 ld[4];

#define ISSUE(t)                                                              \
    do {                                                                      \
        _Pragma("unroll")                                                     \
        for (int it = 0; it < 4; ++it)                                        \
            ld[it] = *(const float4*)(xg + (size_t)(gRow[it] + (t) * 16) * IND + cIt[it]); \
    } while (0)

#define XWRITE(dst)                                                           \
    do {                                                                      \
        _Pragma("unroll")                                                     \
        for (int it = 0; it < 4; ++it) {                                      \
            ushort4 w4;                                                       \
            w4.x = f2bf(ld[it].x); w4.y = f2bf(ld[it].y);                     \
            w4.z = f2bf(ld[it].z); w4.w = f2bf(ld[it].w);                     \
            *(ushort4*)(&(dst)[sIt[it] * XBS + cIt[it]]) = w4;                \
        }                                                                     \
    } while (0)

    // ---- weight fragments, converted in-register (overlap tile-0 staging) --
    bf16x8 w1f[2];
#pragma unroll
    for (int ks = 0; ks < 2; ++ks)
        w1f[ks] = fragW(Wl1, ot * 16 + r, ks * 32 + q * 8);

    bf16x8 w2f[4];
#pragma unroll
    for (int ks = 0; ks < 4; ++ks)
        w2f[ks] = fragW(Wl2, ot * 16 + r, ks * 32 + q * 8);

    const float4 b1s = *(const float4*)(bl1 + ot * 16 + q * 4);
    const float4 b2s = *(const float4*)(bl2 + ot * 16 + q * 4);

    // ---- prologue: tile 0 staged, tile 1 in flight ----
    ISSUE(0);
    XWRITE(xb0);
    ISSUE(1);
    __syncthreads();

    // ======================= phase A: 8 node-tiles =========================
    for (int nt = 0; nt < 8; ++nt) {
        unsigned short* xcur = (nt & 1) ? xb1 : xb0;

        // layer 1 (K=64) for all 8 perturbations of this tile
#pragma unroll
        for (int p = 0; p < PP; ++p) {
            f32x4 a0 = (f32x4){0.f, 0.f, 0.f, 0.f};
#pragma unroll
            for (int ks = 0; ks < 2; ++ks) {
                bf16x8 xf = *(const bf16x8*)(&xcur[(p * 16 + r) * XBS + ks * 32 + q * 8]);
                a0 = mfma16(w1f[ks], xf, a0);
            }
            ushort4 v0;
            v0.x = f2bf(fmaxf(a0[0] + b1s.x, 0.f));
            v0.y = f2bf(fmaxf(a0[1] + b1s.y, 0.f));
            v0.z = f2bf(fmaxf(a0[2] + b1s.z, 0.f));
            v0.w = f2bf(fmaxf(a0[3] + b1s.w, 0.f));
            *(ushort4*)(&h1[(p * 16 + r) * LSTR + ot * 16 + q * 4]) = v0;
        }
        __syncthreads();   // h1 complete (all 128 cols from all 8 waves)

        // layer 2 (K=128), relu-accumulate over perturbations
        f32x4 agg0 = (f32x4){0.f, 0.f, 0.f, 0.f};
#pragma unroll
        for (int p = 0; p < PP; ++p) {
            f32x4 c0 = (f32x4){0.f, 0.f, 0.f, 0.f};
#pragma unroll
            for (int ks = 0; ks < 4; ++ks) {
                bf16x8 hf = *(const bf16x8*)(&h1[(p * 16 + r) * LSTR + ks * 32 + q * 8]);
                c0 = mfma16(w2f[ks], hf, c0);
            }
            agg0[0] += fmaxf(c0[0] + b2s.x, 0.f);
            agg0[1] += fmaxf(c0[1] + b2s.y, 0.f);
            agg0[2] += fmaxf(c0[2] + b2s.z, 0.f);
            agg0[3] += fmaxf(c0[3] + b2s.w, 0.f);
        }
        // agg for node rows nt*16..+16: exclusive (r, col) region per lane
        {
            ushort4 av;
            av.x = f2bf(agg0[0]);
            av.y = f2bf(agg0[1]);
            av.z = f2bf(agg0[2]);
            av.w = f2bf(agg0[3]);
            *(ushort4*)(&aggL[(nt * 16 + r) * LSTR + ot * 16 + q * 4]) = av;
        }

        // stage next tile's x into the other buffer (regs already loaded),
        // then refill regs two tiles ahead. Safe: the end-of-previous-tile
        // barrier guarantees nobody still reads xb[(nt+1)&1].
        if (nt < 7) {
            if (nt & 1) XWRITE(xb0); else XWRITE(xb1);
        }
        if (nt < 6) ISSUE(nt + 2);
        __syncthreads();   // h1 reuse + next xb ready
    }

    // ================= phase B: 4x (Linear+ReLU) + pool ====================
    int cur = 0;
#pragma unroll
    for (int l = 0; l < 4; ++l) {
        const float* Wlf = (l == 0) ? Wg1 : (l == 1) ? Wg2 : (l == 2) ? Wb1 : Wb2;
        const float* bl  = (l == 0) ? bg1 : (l == 1) ? bg2 : (l == 2) ? bb1 : bb2;

        bf16x8 wf[4];
#pragma unroll
        for (int ks = 0; ks < 4; ++ks)
            wf[ks] = fragW(Wlf, ot * 16 + r, ks * 32 + q * 8);

        unsigned short* Xb = cur ? bufB : aggL;
        unsigned short* Yb = cur ? aggL : bufB;

        f32x4 acc[8];
#pragma unroll
        for (int j = 0; j < 8; ++j)
            acc[j] = (f32x4){0.f, 0.f, 0.f, 0.f};

#pragma unroll
        for (int ks = 0; ks < 4; ++ks) {
#pragma unroll
            for (int j = 0; j < 8; ++j) {
                bf16x8 xf = *(const bf16x8*)(&Xb[(j * 16 + r) * LSTR + ks * 32 + q * 8]);
                acc[j] = mfma16(wf[ks], xf, acc[j]);
            }
        }

        if (l < 3) {
            float4 bs = *(const float4*)(bl + ot * 16 + q * 4);
#pragma unroll
            for (int j = 0; j < 8; ++j) {
                ushort4 v;
                v.x = f2bf(fmaxf(acc[j][0] + bs.x, 0.f));
                v.y = f2bf(fmaxf(acc[j][1] + bs.y, 0.f));
                v.z = f2bf(fmaxf(acc[j][2] + bs.z, 0.f));
                v.w = f2bf(fmaxf(acc[j][3] + bs.w, 0.f));
                *(ushort4*)(&Yb[(j * 16 + r) * LSTR + ot * 16 + q * 4]) = v;
            }
            __syncthreads();
            cur ^= 1;
        } else {
            float4 bs = *(const float4*)(bl + ot * 16 + q * 4);
            float s0 = 0.f, s1 = 0.f, s2 = 0.f, s3 = 0.f;
#pragma unroll
            for (int j = 0; j < 8; ++j) {
                s0 += fmaxf(acc[j][0] + bs.x, 0.f);
                s1 += fmaxf(acc[j][1] + bs.y, 0.f);
                s2 += fmaxf(acc[j][2] + bs.z, 0.f);
                s3 += fmaxf(acc[j][3] + bs.w, 0.f);
            }
#pragma unroll
            for (int m = 1; m < 16; m <<= 1) {
                s0 += __shfl_xor(s0, m, 64);
                s1 += __shfl_xor(s1, m, 64);
                s2 += __shfl_xor(s2, m, 64);
                s3 += __shfl_xor(s3, m, 64);
            }
            if (r == 0) {
                pool[ot * 16 + q * 4 + 0] = s0;   // exclusive cols per wave
                pool[ot * 16 + q * 4 + 1] = s1;
                pool[ot * 16 + q * 4 + 2] = s2;
                pool[ot * 16 + q * 4 + 3] = s3;
            }
        }
    }
    __syncthreads();

    // ===================== decoder + log_softmax ===========================
    if (tid < 64) {
        float a0 = bd1[tid], a1 = 0.f, a2 = 0.f, a3 = 0.f;
#pragma unroll
        for (int k = 0; k < 128; k += 4) {
            a0 += pool[k]     * Wd1[(k)     * 64 + tid];
            a1 += pool[k + 1] * Wd1[(k + 1) * 64 + tid];
            a2 += pool[k + 2] * Wd1[(k + 2) * 64 + tid];
            a3 += pool[k + 3] * Wd1[(k + 3) * 64 + tid];
        }
        z[tid] = fmaxf((a0 + a1) + (a2 + a3), 0.f);
    }
    __syncthreads();
    if (tid < OUTD) {
        float b0 = bd2[tid], b1 = 0.f;
#pragma unroll
        for (int k = 0; k < 64; k += 2) {
            b0 += z[k]     * Wd2[(k)     * OUTD + tid];
            b1 += z[k + 1] * Wd2[(k + 1) * OUTD + tid];
        }
        zz[tid] = b0 + b1;
    }
    __syncthreads();
    if (tid == 0) {
        float m = -1e30f;
#pragma unroll
        for (int j = 0; j < OUTD; ++j) m = fmaxf(m, zz[j]);
        float ssum = 0.f;
#pragma unroll
        for (int j = 0; j < OUTD; ++j) ssum += expf(zz[j] - m);
        float ls = logf(ssum);
#pragma unroll
        for (int j = 0; j < OUTD; ++j) out[g * OUTD + j] = zz[j] - m - ls;
    }
#undef ISSUE
#undef XWRITE
}

extern "C" void kernel_launch(void* const* d_in, const int* in_sizes, int n_in,
                              void* d_out, int out_size, void* d_ws, size_t ws_size,
                              hipStream_t stream) {
    const float* x   = (const float*)d_in[0];
    // d_in[1] = ptr (unused; structure is static)
    const float* Wl1 = (const float*)d_in[2];
    const float* bl1 = (const float*)d_in[3];
    const float* Wl2 = (const float*)d_in[4];
    const float* bl2 = (const float*)d_in[5];
    const float* Wg1 = (const float*)d_in[6];
    const float* bg1 = (const float*)d_in[7];
    const float* Wg2 = (const float*)d_in[8];
    const float* bg2 = (const float*)d_in[9];
    const float* Wb1 = (const float*)d_in[10];
    const float* bb1 = (const float*)d_in[11];
    const float* Wb2 = (const float*)d_in[12];
    const float* bb2 = (const float*)d_in[13];
    const float* Wd1 = (const float*)d_in[14];
    const float* bd1 = (const float*)d_in[15];
    const float* Wd2 = (const float*)d_in[16];
    const float* bd2 = (const float*)d_in[17];

    // Single launch: weights converted in-kernel; workspace unused.
    graph_fused<<<NG, 512, 0, stream>>>(x,
                                        Wl1, bl1, Wl2, bl2,
                                        Wg1, bg1, Wg2, bg2,
                                        Wb1, bb1, Wb2, bb2,
                                        Wd1, bd1, Wd2, bd2, (float*)d_out);
}

// Round 12
// 141.760 us; speedup vs baseline: 1.1541x; 1.0129x over previous
//
#include <hip/hip_runtime.h>
#include <stdint.h>

// Problem constants (static per reference)
#define NG    256    // graphs
#define NPG   128    // nodes per graph
#define PP    8      // perturbations
#define IND   64     // input dim
#define HID   128    // hidden
#define OUTD  10     // classes

typedef short bf16x8 __attribute__((ext_vector_type(8)));
typedef float f32x4  __attribute__((ext_vector_type(4)));

// RNE f32->bf16 (bit trick) — the verified-correct conversion on this path.
static __device__ __forceinline__ unsigned short f2bf(float f) {
    unsigned int u = __float_as_uint(f);
    u += 0x7FFFu + ((u >> 16) & 1u);
    return (unsigned short)(u >> 16);
}

static __device__ __forceinline__ f32x4 mfma16(bf16x8 a, bf16x8 b, f32x4 c) {
    return __builtin_amdgcn_mfma_f32_16x16x32_bf16(a, b, c, 0, 0, 0);
}

// Barrier that drains ONLY LDS (lgkmcnt), not global loads (vmcnt).
// __syncthreads() emits s_waitcnt vmcnt(0) lgkmcnt(0) before s_barrier, which
// drains the x-prefetch burst (32 KB/block/tile) EVERY tile — measured as the
// ~70K-cycle gap between the compute model (~30K cyc) and the invariant 42 us
// (r7/r8/r9 falsified barriers/waves/LDS-BW; the drain convoy explains all
// three invariances). All cross-wave hazards in this kernel are LDS-only; the
// only in-loop global traffic is read-only x, whose consumption is ordered by
// the compiler's automatic register-dependency vmcnt at XWRITE. sched_barrier
// fences (rule #18) pin instruction motion across the asm waitcnt + barrier.
static __device__ __forceinline__ void lbar() {
    asm volatile("s_waitcnt lgkmcnt(0)" ::: "memory");
    __builtin_amdgcn_sched_barrier(0);
    __builtin_amdgcn_s_barrier();
    __builtin_amdgcn_sched_barrier(0);
}

// Build one bf16x8 A-fragment directly from the f32 weight matrix W[k][out]
// (k-major, HID out-cols): elements k0..k0+7 of column outc. Identical f2bf
// on identical f32 values as the old prep_weights kernel -> bit-identical.
static __device__ __forceinline__ bf16x8 fragW(const float* __restrict__ W,
                                               int outc, int k0) {
    bf16x8 f;
#pragma unroll
    for (int j = 0; j < 8; ++j)
        f[j] = (short)f2bf(W[(size_t)(k0 + j) * HID + outc]);
    return f;
}

#define LSTR 136   // bf16 LDS row stride for 128-col tiles (272 B): 68 words
                   // == 4 mod 32 -> only 2-way bank aliasing (free)
#define XBS  72    // x-slab stride (64 cols + pad): 36 words == 4 mod 32, same

// ---------------------------------------------------------------------------
// Fused kernel: ONE BLOCK PER GRAPH (256 blocks x 512 threads = 8 waves).
// Round-11 kernel (single launch, in-kernel weight conversion) with ONE
// change: every __syncthreads() -> lbar() (lgkmcnt-only barrier), so the
// 2-tile-ahead x prefetch actually stays in flight across barriers instead
// of being drained by vmcnt(0) at every tile boundary.
// ---------------------------------------------------------------------------
__global__ __launch_bounds__(512) void graph_fused(
    const float* __restrict__ x,
    const float* __restrict__ Wl1, const float* __restrict__ bl1,
    const float* __restrict__ Wl2, const float* __restrict__ bl2,
    const float* __restrict__ Wg1, const float* __restrict__ bg1,
    const float* __restrict__ Wg2, const float* __restrict__ bg2,
    const float* __restrict__ Wb1, const float* __restrict__ bb1,
    const float* __restrict__ Wb2, const float* __restrict__ bb2,
    const float* __restrict__ Wd1, const float* __restrict__ bd1,
    const float* __restrict__ Wd2, const float* __restrict__ bd2,
    float* __restrict__ out)
{
    // LDS map (bytes):
    //   [0)      xb0 128*XBS shorts (18432) \  phase A x dbuf; aliased by
    //   [18432)  xb1 128*XBS shorts (18432) /  bufB (34816 B) in phase B
    //   [36864)  h1   128*LSTR shorts (34816)
    //   [71680)  aggL 128*LSTR shorts (34816)
    //   [106496) pool 128 f32 (512)
    //   [107008) z    64 f32  (256)
    //   [107264) zz   16 f32  (64)
    __shared__ __align__(16) unsigned char smem[107328];
    unsigned short* xb0  = (unsigned short*)(smem);
    unsigned short* xb1  = (unsigned short*)(smem + 18432);
    unsigned short* h1   = (unsigned short*)(smem + 36864);
    unsigned short* aggL = (unsigned short*)(smem + 71680);
    unsigned short* bufB = (unsigned short*)(smem);            // phase-B ping
    float* pool = (float*)(smem + 106496);
    float* z    = (float*)(smem + 107008);
    float* zz   = (float*)(smem + 107264);

    const int g    = blockIdx.x;
    const int tid  = threadIdx.x;
    const int wave = tid >> 6;     // 0..7
    const int lane = tid & 63;
    const int q    = lane >> 4;
    const int r    = lane & 15;
    const int ot   = wave;         // each wave owns output cols [16*ot, 16*ot+16)

    const float* xg = x + (size_t)g * (NPG * PP) * IND;

    // ---- per-thread staging geometry: 8192 elems/tile, 16 per thread ----
    int sIt[4], cIt[4], gRow[4];
#pragma unroll
    for (int it = 0; it < 4; ++it) {
        int e = it * 2048 + tid * 4;       // element index in the tile slab
        int s = e >> 6;                    // LDS row (p*16 + rr)
        sIt[it]  = s;
        cIt[it]  = e & 63;
        gRow[it] = (s >> 4) * 128 + (s & 15);   // global row sans nt*16
    }
    float4 ld[4];

#define ISSUE(t)                                                              \
    do {                                                                      \
        _Pragma("unroll")                                                     \
        for (int it = 0; it < 4; ++it)                                        \
            ld[it] = *(const float4*)(xg + (size_t)(gRow[it] + (t) * 16) * IND + cIt[it]); \
    } while (0)

#define XWRITE(dst)                                                           \
    do {                                                                      \
        _Pragma("unroll")                                                     \
        for (int it = 0; it < 4; ++it) {                                      \
            ushort4 w4;                                                       \
            w4.x = f2bf(ld[it].x); w4.y = f2bf(ld[it].y);                     \
            w4.z = f2bf(ld[it].z); w4.w = f2bf(ld[it].w);                     \
            *(ushort4*)(&(dst)[sIt[it] * XBS + cIt[it]]) = w4;                \
        }                                                                     \
    } while (0)

    // ---- weight fragments, converted in-register (overlap tile-0 staging) --
    bf16x8 w1f[2];
#pragma unroll
    for (int ks = 0; ks < 2; ++ks)
        w1f[ks] = fragW(Wl1, ot * 16 + r, ks * 32 + q * 8);

    bf16x8 w2f[4];
#pragma unroll
    for (int ks = 0; ks < 4; ++ks)
        w2f[ks] = fragW(Wl2, ot * 16 + r, ks * 32 + q * 8);

    const float4 b1s = *(const float4*)(bl1 + ot * 16 + q * 4);
    const float4 b2s = *(const float4*)(bl2 + ot * 16 + q * 4);

    // ---- prologue: tile 0 staged, tile 1 in flight ----
    ISSUE(0);
    XWRITE(xb0);   // compiler inserts vmcnt wait for ld use (register dep)
    ISSUE(1);
    lbar();        // tile-1 loads stay in flight across

    // ======================= phase A: 8 node-tiles =========================
    for (int nt = 0; nt < 8; ++nt) {
        unsigned short* xcur = (nt & 1) ? xb1 : xb0;

        // layer 1 (K=64) for all 8 perturbations of this tile
#pragma unroll
        for (int p = 0; p < PP; ++p) {
            f32x4 a0 = (f32x4){0.f, 0.f, 0.f, 0.f};
#pragma unroll
            for (int ks = 0; ks < 2; ++ks) {
                bf16x8 xf = *(const bf16x8*)(&xcur[(p * 16 + r) * XBS + ks * 32 + q * 8]);
                a0 = mfma16(w1f[ks], xf, a0);
            }
            ushort4 v0;
            v0.x = f2bf(fmaxf(a0[0] + b1s.x, 0.f));
            v0.y = f2bf(fmaxf(a0[1] + b1s.y, 0.f));
            v0.z = f2bf(fmaxf(a0[2] + b1s.z, 0.f));
            v0.w = f2bf(fmaxf(a0[3] + b1s.w, 0.f));
            *(ushort4*)(&h1[(p * 16 + r) * LSTR + ot * 16 + q * 4]) = v0;
        }
        lbar();   // h1 complete (all 128 cols); x loads remain in flight

        // layer 2 (K=128), relu-accumulate over perturbations
        f32x4 agg0 = (f32x4){0.f, 0.f, 0.f, 0.f};
#pragma unroll
        for (int p = 0; p < PP; ++p) {
            f32x4 c0 = (f32x4){0.f, 0.f, 0.f, 0.f};
#pragma unroll
            for (int ks = 0; ks < 4; ++ks) {
                bf16x8 hf = *(const bf16x8*)(&h1[(p * 16 + r) * LSTR + ks * 32 + q * 8]);
                c0 = mfma16(w2f[ks], hf, c0);
            }
            agg0[0] += fmaxf(c0[0] + b2s.x, 0.f);
            agg0[1] += fmaxf(c0[1] + b2s.y, 0.f);
            agg0[2] += fmaxf(c0[2] + b2s.z, 0.f);
            agg0[3] += fmaxf(c0[3] + b2s.w, 0.f);
        }
        // agg for node rows nt*16..+16: exclusive (r, col) region per lane
        {
            ushort4 av;
            av.x = f2bf(agg0[0]);
            av.y = f2bf(agg0[1]);
            av.z = f2bf(agg0[2]);
            av.w = f2bf(agg0[3]);
            *(ushort4*)(&aggL[(nt * 16 + r) * LSTR + ot * 16 + q * 4]) = av;
        }

        // stage next tile's x (XWRITE consumes the in-flight loads via the
        // compiler's register-dep vmcnt — they've had a full tile to land),
        // then refill regs two tiles ahead.
        if (nt < 7) {
            if (nt & 1) XWRITE(xb0); else XWRITE(xb1);
        }
        if (nt < 6) ISSUE(nt + 2);
        lbar();   // h1 reuse + next xb ready; fresh loads NOT drained
    }

    // ================= phase B: 4x (Linear+ReLU) + pool ====================
    int cur = 0;
#pragma unroll
    for (int l = 0; l < 4; ++l) {
        const float* Wlf = (l == 0) ? Wg1 : (l == 1) ? Wg2 : (l == 2) ? Wb1 : Wb2;
        const float* bl  = (l == 0) ? bg1 : (l == 1) ? bg2 : (l == 2) ? bb1 : bb2;

        bf16x8 wf[4];
#pragma unroll
        for (int ks = 0; ks < 4; ++ks)
            wf[ks] = fragW(Wlf, ot * 16 + r, ks * 32 + q * 8);

        unsigned short* Xb = cur ? bufB : aggL;
        unsigned short* Yb = cur ? aggL : bufB;

        f32x4 acc[8];
#pragma unroll
        for (int j = 0; j < 8; ++j)
            acc[j] = (f32x4){0.f, 0.f, 0.f, 0.f};

#pragma unroll
        for (int ks = 0; ks < 4; ++ks) {
#pragma unroll
            for (int j = 0; j < 8; ++j) {
                bf16x8 xf = *(const bf16x8*)(&Xb[(j * 16 + r) * LSTR + ks * 32 + q * 8]);
                acc[j] = mfma16(wf[ks], xf, acc[j]);
            }
        }

        if (l < 3) {
            float4 bs = *(const float4*)(bl + ot * 16 + q * 4);
#pragma unroll
            for (int j = 0; j < 8; ++j) {
                ushort4 v;
                v.x = f2bf(fmaxf(acc[j][0] + bs.x, 0.f));
                v.y = f2bf(fmaxf(acc[j][1] + bs.y, 0.f));
                v.z = f2bf(fmaxf(acc[j][2] + bs.z, 0.f));
                v.w = f2bf(fmaxf(acc[j][3] + bs.w, 0.f));
                *(ushort4*)(&Yb[(j * 16 + r) * LSTR + ot * 16 + q * 4]) = v;
            }
            lbar();
            cur ^= 1;
        } else {
            float4 bs = *(const float4*)(bl + ot * 16 + q * 4);
            float s0 = 0.f, s1 = 0.f, s2 = 0.f, s3 = 0.f;
#pragma unroll
            for (int j = 0; j < 8; ++j) {
                s0 += fmaxf(acc[j][0] + bs.x, 0.f);
                s1 += fmaxf(acc[j][1] + bs.y, 0.f);
                s2 += fmaxf(acc[j][2] + bs.z, 0.f);
                s3 += fmaxf(acc[j][3] + bs.w, 0.f);
            }
#pragma unroll
            for (int m = 1; m < 16; m <<= 1) {
                s0 += __shfl_xor(s0, m, 64);
                s1 += __shfl_xor(s1, m, 64);
                s2 += __shfl_xor(s2, m, 64);
                s3 += __shfl_xor(s3, m, 64);
            }
            if (r == 0) {
                pool[ot * 16 + q * 4 + 0] = s0;   // exclusive cols per wave
                pool[ot * 16 + q * 4 + 1] = s1;
                pool[ot * 16 + q * 4 + 2] = s2;
                pool[ot * 16 + q * 4 + 3] = s3;
            }
        }
    }
    lbar();

    // ===================== decoder + log_softmax ===========================
    if (tid < 64) {
        float a0 = bd1[tid], a1 = 0.f, a2 = 0.f, a3 = 0.f;
#pragma unroll
        for (int k = 0; k < 128; k += 4) {
            a0 += pool[k]     * Wd1[(k)     * 64 + tid];
            a1 += pool[k + 1] * Wd1[(k + 1) * 64 + tid];
            a2 += pool[k + 2] * Wd1[(k + 2) * 64 + tid];
            a3 += pool[k + 3] * Wd1[(k + 3) * 64 + tid];
        }
        z[tid] = fmaxf((a0 + a1) + (a2 + a3), 0.f);
    }
    lbar();
    if (tid < OUTD) {
        float b0 = bd2[tid], b1 = 0.f;
#pragma unroll
        for (int k = 0; k < 64; k += 2) {
            b0 += z[k]     * Wd2[(k)     * OUTD + tid];
            b1 += z[k + 1] * Wd2[(k + 1) * OUTD + tid];
        }
        zz[tid] = b0 + b1;
    }
    lbar();
    if (tid == 0) {
        float m = -1e30f;
#pragma unroll
        for (int j = 0; j < OUTD; ++j) m = fmaxf(m, zz[j]);
        float ssum = 0.f;
#pragma unroll
        for (int j = 0; j < OUTD; ++j) ssum += expf(zz[j] - m);
        float ls = logf(ssum);
#pragma unroll
        for (int j = 0; j < OUTD; ++j) out[g * OUTD + j] = zz[j] - m - ls;
    }
#undef ISSUE
#undef XWRITE
}

extern "C" void kernel_launch(void* const* d_in, const int* in_sizes, int n_in,
                              void* d_out, int out_size, void* d_ws, size_t ws_size,
                              hipStream_t stream) {
    const float* x   = (const float*)d_in[0];
    // d_in[1] = ptr (unused; structure is static)
    const float* Wl1 = (const float*)d_in[2];
    const float* bl1 = (const float*)d_in[3];
    const float* Wl2 = (const float*)d_in[4];
    const float* bl2 = (const float*)d_in[5];
    const float* Wg1 = (const float*)d_in[6];
    const float* bg1 = (const float*)d_in[7];
    const float* Wg2 = (const float*)d_in[8];
    const float* bg2 = (const float*)d_in[9];
    const float* Wb1 = (const float*)d_in[10];
    const float* bb1 = (const float*)d_in[11];
    const float* Wb2 = (const float*)d_in[12];
    const float* bb2 = (const float*)d_in[13];
    const float* Wd1 = (const float*)d_in[14];
    const float* bd1 = (const float*)d_in[15];
    const float* Wd2 = (const float*)d_in[16];
    const float* bd2 = (const float*)d_in[17];

    // Single launch: weights converted in-kernel; workspace unused.
    graph_fused<<<NG, 512, 0, stream>>>(x,
                                        Wl1, bl1, Wl2, bl2,
                                        Wg1, bg1, Wg2, bg2,
                                        Wb1, bb1, Wb2, bb2,
                                        Wd1, bd1, Wd2, bd2, (float*)d_out);
}